// Round 6
// baseline (55.116 us; speedup 1.0000x reference)
//
#include <hip/hip_runtime.h>
#include <hip/hip_bf16.h>

// y = upsample_nearest_2x2x2(conv1x1(x,W,b)) == conv on small grid + replicate 8x.
// x: [2][320][16][32][32] f32, W: [160][320] f32, b: [160] f32 -> out: [2][160][32][64][64] f32
//
// v6: store-interleaved structure. X tile (64 s x 320 k bf16) staged once in LDS;
// all 10 B-fragments hoisted to registers; M-tile loop loads W fragments directly
// from a fragment-ordered bf16 image (d_ws, built by wprep) and stores each M-tile
// immediately -> HBM writes flow through ~80% of the kernel instead of a tail burst.

#define CI      320
#define CO      160
#define S_IN    16384       // 16*32*32
#define NT      64          // spatial tile per block
#define NST     10          // K-steps (CI/32)
#define NMT     10          // M-tiles (CO/16)
#define XPITCHB 656         // X LDS row pitch bytes (41*16; 164 words % 32 = 4 -> 2-way reads)
#define WS_B    (NMT * NST * 64 * 16)   // 102400 bytes W image

typedef __attribute__((ext_vector_type(8))) short short8;
typedef __attribute__((ext_vector_type(4))) float f32x4;

union frag_cast { uint4 u; short8 s; };

static __device__ __forceinline__ unsigned short f2bf(float f) {
    __hip_bfloat16 h = __float2bfloat16(f);   // RNE
    unsigned short u;
    __builtin_memcpy(&u, &h, 2);
    return u;
}
static __device__ __forceinline__ unsigned int pack2(float lo, float hi) {
    return (unsigned int)f2bf(lo) | ((unsigned int)f2bf(hi) << 16);
}

// ---- pre-kernel: fragment-ordered bf16 W image ----
// u32 i: wrd=i&3, lane=(i>>2)&63, grp=i>>8 (0..99): st=grp%10, mt=grp/10.
// frow=lane&15, fk=lane>>4; o=mt*16+frow; k=st*32+fk*8+wrd*2.
__global__ __launch_bounds__(256) void wprep_kernel(
    const float* __restrict__ Wm, unsigned int* __restrict__ ws)
{
    const int i    = blockIdx.x * 256 + threadIdx.x;  // 0..25599
    const int wrd  = i & 3;
    const int lane = (i >> 2) & 63;
    const int grp  = i >> 8;
    const int st   = grp % 10;
    const int mt   = grp / 10;
    const int o    = mt * 16 + (lane & 15);
    const int k    = st * 32 + (lane >> 4) * 8 + wrd * 2;
    ws[i] = pack2(Wm[o * CI + k], Wm[o * CI + k + 1]);
}

template<bool USE_WS>
__global__ __launch_bounds__(256, 2) void fused_upconv_v6(
    const float* __restrict__ x,
    const float* __restrict__ Wm,
    const float* __restrict__ bias,
    const unsigned int* __restrict__ wsW,
    float* __restrict__ out)
{
    __shared__ __align__(16) char Xs[NT * XPITCHB];   // 41,984 B

    const int t    = threadIdx.x;
    const int bx   = blockIdx.x;        // 0..511
    const int tile = bx >> 1;           // 0..255
    const int b    = bx & 1;
    const int s_base = tile * NT;
    const float* xb  = x + (size_t)b * CI * S_IN;

    const int lane = t & 63;
    const int wid  = t >> 6;            // wave -> 16-s subtile
    const int frow = lane & 15;
    const int fk   = lane >> 4;

    // ---- phase 1: stage X tile (f32 -> bf16, [k][s] -> [s][k]) ----
    // it 0..9: idx = t + it*256; kp = idx>>4 (k-pair 0..159), sq = idx&15.
    #pragma unroll
    for (int it = 0; it < 10; ++it) {
        const int idx = t + it * 256;
        const int kp  = idx >> 4;
        const int sq  = idx & 15;
        const float4 a0 = *(const float4*)&xb[(size_t)(2 * kp)     * S_IN + s_base + sq * 4];
        const float4 a1 = *(const float4*)&xb[(size_t)(2 * kp + 1) * S_IN + s_base + sq * 4];
        const float e0[4] = {a0.x, a0.y, a0.z, a0.w};
        const float e1[4] = {a1.x, a1.y, a1.z, a1.w};
        #pragma unroll
        for (int j = 0; j < 4; ++j)
            *(unsigned int*)&Xs[(sq * 4 + j) * XPITCHB + kp * 4] = pack2(e0[j], e1[j]);
    }
    __syncthreads();

    // ---- hoist B-fragments (X) into registers: 10 x short8 ----
    short8 bfrag[NST];
    {
        const char* xrow = &Xs[(wid * 16 + frow) * XPITCHB + fk * 16];
        #pragma unroll
        for (int st = 0; st < NST; ++st)
            bfrag[st] = *(const short8*)(xrow + st * 64);
    }

    // ---- phase 2: per-M-tile K-sweep + immediate store, W frags ping-ponged ----
    const int dd  = (s_base + wid * 16 + frow) >> 10;
    const int hh  = ((s_base + wid * 16 + frow) >> 5) & 31;
    const int wc0 = (s_base + wid * 16 + frow) & 30;   // wc & ~1
    const int odd = lane & 1;

    short8 afA[NST], afB[NST];

    auto load_af = [&](short8* af, int mt) {
        if constexpr (USE_WS) {
            const char* base = (const char*)wsW + ((size_t)(mt * NST) * 64 + lane) * 16;
            #pragma unroll
            for (int st = 0; st < NST; ++st)
                af[st] = *(const short8*)(base + (size_t)st * 1024);
        } else {
            const int o = mt * 16 + frow;
            #pragma unroll
            for (int st = 0; st < NST; ++st) {
                const float4 f0 = *(const float4*)&Wm[(size_t)o * CI + st * 32 + fk * 8];
                const float4 f1 = *(const float4*)&Wm[(size_t)o * CI + st * 32 + fk * 8 + 4];
                frag_cast fc;
                fc.u = (uint4){pack2(f0.x, f0.y), pack2(f0.z, f0.w),
                               pack2(f1.x, f1.y), pack2(f1.z, f1.w)};
                af[st] = fc.s;
            }
        }
    };

    auto compute_store = [&](const short8* af, int mt) {
        f32x4 acc0 = {0.f, 0.f, 0.f, 0.f};
        f32x4 acc1 = {0.f, 0.f, 0.f, 0.f};
        #pragma unroll
        for (int st = 0; st < NST; st += 2) {
            acc0 = __builtin_amdgcn_mfma_f32_16x16x32_bf16(af[st],     bfrag[st],     acc0, 0, 0, 0);
            acc1 = __builtin_amdgcn_mfma_f32_16x16x32_bf16(af[st + 1], bfrag[st + 1], acc1, 0, 0, 0);
        }
        const float4 bv = *(const float4*)&bias[mt * 16 + fk * 4];
        const float bvj[4] = {bv.x, bv.y, bv.z, bv.w};
        #pragma unroll
        for (int j = 0; j < 4; ++j) {
            const int o = mt * 16 + fk * 4 + j;     // D row = fk*4 + j
            float v  = acc0[j] + acc1[j] + bvj[j];
            float vp = __shfl_xor(v, 1);
            float lo = odd ? vp : v;
            float hi = odd ? v : vp;
            f32x4 q = {lo, lo, hi, hi};
            const size_t base = (((size_t)(b * CO + o) * 32) + (size_t)(2 * dd + odd)) * 4096
                              + (size_t)(2 * hh) * 64 + (size_t)(2 * wc0);
            __builtin_nontemporal_store(q, (f32x4*)&out[base]);
            __builtin_nontemporal_store(q, (f32x4*)&out[base + 64]);
        }
    };

    load_af(afA, 0);
    #pragma unroll
    for (int mt = 0; mt < NMT; mt += 2) {
        load_af(afB, mt + 1);           // issue next tile's W loads
        compute_store(afA, mt);         // MFMA + stores overlap them
        if (mt + 2 < NMT) load_af(afA, mt + 2);
        compute_store(afB, mt + 1);
    }
}

extern "C" void kernel_launch(void* const* d_in, const int* in_sizes, int n_in,
                              void* d_out, int out_size, void* d_ws, size_t ws_size,
                              hipStream_t stream) {
    const float* x    = (const float*)d_in[0];
    const float* Wm   = (const float*)d_in[1];
    const float* bias = (const float*)d_in[2];
    float* out        = (float*)d_out;

    dim3 block(256);
    if (ws_size >= (size_t)WS_B && d_ws != nullptr) {
        unsigned int* ws = (unsigned int*)d_ws;
        wprep_kernel<<<dim3(100), block, 0, stream>>>(Wm, ws);
        fused_upconv_v6<true><<<dim3(512), block, 0, stream>>>(x, Wm, bias, ws, out);
    } else {
        fused_upconv_v6<false><<<dim3(512), block, 0, stream>>>(x, Wm, bias, nullptr, out);
    }
}

// Round 7
// 45.797 us; speedup vs baseline: 1.2035x; 1.2035x over previous
//
#include <hip/hip_runtime.h>
#include <hip/hip_bf16.h>

// y = upsample_nearest_2x2x2(conv1x1(x,W,b)) == conv on small grid + replicate 8x.
// x: [2][320][16][32][32] f32, W: [160][320] f32, b: [160] f32 -> out: [2][160][32][64][64] f32
//
// v7: NT=32, 1024 blocks (4 blocks/CU). W lives in REGISTERS as ready bf16 MFMA
// fragments loaded from a fragment-ordered image in d_ws (built by wprep): no W
// VALU, no W LDS. X double-buffered in 9 KB LDS, one barrier per chunk. Wave =
// (s-half 16s, o-half 80o); 5 M-tiles x K=320 via 10 MFMA per chunk pair.

#define CI      320
#define CO      160
#define S_IN    16384        // 16*32*32
#define NT      32           // spatial tile per block
#define KC      64           // K chunk = 2 MFMA K-steps
#define NCH     (CI / KC)    // 5
#define MTW     5            // M-tiles per wave (80 o)
#define XPITCH  144          // X LDS row pitch bytes (128 data + 16 pad -> 2-way free b128)
#define WS_B    (100 * 64 * 16)   // 102400 B fragment-ordered W image

typedef __attribute__((ext_vector_type(8))) short short8;
typedef __attribute__((ext_vector_type(4))) float f32x4;

union frag_cast { uint4 u; short8 s; };

static __device__ __forceinline__ unsigned short f2bf(float f) {
    __hip_bfloat16 h = __float2bfloat16(f);   // RNE
    unsigned short u;
    __builtin_memcpy(&u, &h, 2);
    return u;
}
static __device__ __forceinline__ unsigned int pack2(float lo, float hi) {
    return (unsigned int)f2bf(lo) | ((unsigned int)f2bf(hi) << 16);
}

// ---- pre-kernel: fragment-ordered bf16 W image (same layout as r6, verified) ----
// u32 i: wrd=i&3, lane=(i>>2)&63, grp=i>>8 (0..99): st=grp%10, mt=grp/10.
// elem = Wbf[mt*16+(lane&15)][st*32+(lane>>4)*8+wrd*2 (+1)]
__global__ __launch_bounds__(256) void wprep_kernel(
    const float* __restrict__ Wm, unsigned int* __restrict__ ws)
{
    const int i    = blockIdx.x * 256 + threadIdx.x;  // 0..25599
    const int wrd  = i & 3;
    const int lane = (i >> 2) & 63;
    const int grp  = i >> 8;
    const int st   = grp % 10;
    const int mt   = grp / 10;
    const int o    = mt * 16 + (lane & 15);
    const int k    = st * 32 + (lane >> 4) * 8 + wrd * 2;
    ws[i] = pack2(Wm[o * CI + k], Wm[o * CI + k + 1]);
}

template<bool USE_WS>
__global__ __launch_bounds__(256, 4) void fused_upconv_v7(
    const float* __restrict__ x,
    const float* __restrict__ Wm,
    const float* __restrict__ bias,
    const unsigned int* __restrict__ wsW,
    float* __restrict__ out)
{
    __shared__ __align__(16) char Xs[2][NT * XPITCH];   // 2 x 4608 B

    const int t    = threadIdx.x;
    const int bx   = blockIdx.x;          // 0..1023
    const int tile = bx >> 1;             // 0..511
    const int b    = bx & 1;
    const int s_base = tile * NT;
    const float* xb  = x + (size_t)b * CI * S_IN;

    const int lane = t & 63;
    const int wid  = t >> 6;
    const int sh   = wid & 1;             // s-half (16 s)
    const int ohh  = wid >> 1;            // o-half (80 o)
    const int frow = lane & 15;
    const int fk   = lane >> 4;
    const int o_base = ohh * 80;

    // X staging map: kp = t>>3 (32 k-pairs), sq = t&7 (s-quads)
    const int kp = t >> 3;
    const int sq = t & 7;

    float4 xr0, xr1;
    short8 afr[2 * MTW];                  // W fragments for current chunk (10 x 16B)

    // ---- prologue: X(0) and W(0) ----
    xr0 = *(const float4*)&xb[(size_t)(2 * kp)     * S_IN + s_base + sq * 4];
    xr1 = *(const float4*)&xb[(size_t)(2 * kp + 1) * S_IN + s_base + sq * 4];

    #pragma unroll
    for (int m = 0; m < MTW; ++m) {
        if constexpr (USE_WS) {
            const char* p = (const char*)wsW + ((size_t)((ohh * 5 + m) * 10) * 64 + lane) * 16;
            afr[2 * m]     = *(const short8*)p;
            afr[2 * m + 1] = *(const short8*)(p + 64 * 16);
        } else {
            const int o = o_base + m * 16 + frow;
            #pragma unroll
            for (int stl = 0; stl < 2; ++stl) {
                const int k0 = stl * 32 + fk * 8;
                const float4 f0 = *(const float4*)&Wm[(size_t)o * CI + k0];
                const float4 f1 = *(const float4*)&Wm[(size_t)o * CI + k0 + 4];
                frag_cast fc;
                fc.u = (uint4){pack2(f0.x, f0.y), pack2(f0.z, f0.w),
                               pack2(f1.x, f1.y), pack2(f1.z, f1.w)};
                afr[2 * m + stl] = fc.s;
            }
        }
    }

    f32x4 acc[MTW];
    #pragma unroll
    for (int m = 0; m < MTW; ++m) acc[m] = (f32x4){0.f, 0.f, 0.f, 0.f};

    const char* xrow_base0 = &Xs[0][(sh * 16 + frow) * XPITCH + fk * 16];
    const char* xrow_base1 = &Xs[1][(sh * 16 + frow) * XPITCH + fk * 16];

    for (int c = 0; c < NCH; ++c) {
        // stage X(c): f32 regs -> bf16 LDS ([k][s] -> [s][k] transpose)
        {
            char* buf = Xs[c & 1];
            const float e0[4] = {xr0.x, xr0.y, xr0.z, xr0.w};
            const float e1[4] = {xr1.x, xr1.y, xr1.z, xr1.w};
            #pragma unroll
            for (int j = 0; j < 4; ++j)
                *(unsigned int*)&buf[(sq * 4 + j) * XPITCH + kp * 4] = pack2(e0[j], e1[j]);
        }
        // issue X(c+1) loads (consumed next iteration)
        if (c + 1 < NCH) {
            const int kc = (c + 1) * KC;
            xr0 = *(const float4*)&xb[(size_t)(kc + 2 * kp)     * S_IN + s_base + sq * 4];
            xr1 = *(const float4*)&xb[(size_t)(kc + 2 * kp + 1) * S_IN + s_base + sq * 4];
        }
        __syncthreads();

        const char* xrow = (c & 1) ? xrow_base1 : xrow_base0;
        const short8 b0 = *(const short8*)(xrow);        // st local 0 (k 0..31 of chunk)
        const short8 b1 = *(const short8*)(xrow + 64);   // st local 1

        #pragma unroll
        for (int m = 0; m < MTW; ++m) {
            acc[m] = __builtin_amdgcn_mfma_f32_16x16x32_bf16(afr[2 * m],     b0, acc[m], 0, 0, 0);
            acc[m] = __builtin_amdgcn_mfma_f32_16x16x32_bf16(afr[2 * m + 1], b1, acc[m], 0, 0, 0);
            // reload this m-tile's fragments for chunk c+1 (just-after-use pipelining)
            if (c + 1 < NCH) {
                if constexpr (USE_WS) {
                    const char* p = (const char*)wsW
                        + ((size_t)((ohh * 5 + m) * 10 + (c + 1) * 2) * 64 + lane) * 16;
                    afr[2 * m]     = *(const short8*)p;
                    afr[2 * m + 1] = *(const short8*)(p + 64 * 16);
                } else {
                    const int o = o_base + m * 16 + frow;
                    #pragma unroll
                    for (int stl = 0; stl < 2; ++stl) {
                        const int k0 = (c + 1) * KC + stl * 32 + fk * 8;
                        const float4 f0 = *(const float4*)&Wm[(size_t)o * CI + k0];
                        const float4 f1 = *(const float4*)&Wm[(size_t)o * CI + k0 + 4];
                        frag_cast fc;
                        fc.u = (uint4){pack2(f0.x, f0.y), pack2(f0.z, f0.w),
                                       pack2(f1.x, f1.y), pack2(f1.z, f1.w)};
                        afr[2 * m + stl] = fc.s;
                    }
                }
            }
        }
    }

    // ---- epilogue: bias + replicate 8x; shfl-pair -> full float4 nontemporal stores ----
    const int sidx = sh * 16 + frow;          // 0..31 == small w within this block's row
    const int s    = s_base + sidx;
    const int dd   = s >> 10;
    const int hh   = (s >> 5) & 31;
    const int wc0  = sidx & ~1;
    const int odd  = lane & 1;

    #pragma unroll
    for (int m = 0; m < MTW; ++m) {
        const float4 bv = *(const float4*)&bias[o_base + m * 16 + fk * 4];
        const float bvj[4] = {bv.x, bv.y, bv.z, bv.w};
        #pragma unroll
        for (int j = 0; j < 4; ++j) {
            const int o = o_base + m * 16 + fk * 4 + j;     // D row = o
            float v  = acc[m][j] + bvj[j];
            float vp = __shfl_xor(v, 1);
            float lo = odd ? vp : v;
            float hi = odd ? v : vp;
            f32x4 q = {lo, lo, hi, hi};
            // even lane -> d-row 2dd, odd lane -> 2dd+1; each writes h-rows 2hh, 2hh+1
            const size_t base = (((size_t)(b * CO + o) * 32) + (size_t)(2 * dd + odd)) * 4096
                              + (size_t)(2 * hh) * 64 + (size_t)(2 * wc0);
            __builtin_nontemporal_store(q, (f32x4*)&out[base]);
            __builtin_nontemporal_store(q, (f32x4*)&out[base + 64]);
        }
    }
}

extern "C" void kernel_launch(void* const* d_in, const int* in_sizes, int n_in,
                              void* d_out, int out_size, void* d_ws, size_t ws_size,
                              hipStream_t stream) {
    const float* x    = (const float*)d_in[0];
    const float* Wm   = (const float*)d_in[1];
    const float* bias = (const float*)d_in[2];
    float* out        = (float*)d_out;

    dim3 block(256);
    if (ws_size >= (size_t)WS_B && d_ws != nullptr) {
        unsigned int* ws = (unsigned int*)d_ws;
        wprep_kernel<<<dim3(100), block, 0, stream>>>(Wm, ws);
        fused_upconv_v7<true><<<dim3(1024), block, 0, stream>>>(x, Wm, bias, ws, out);
    } else {
        fused_upconv_v7<false><<<dim3(1024), block, 0, stream>>>(x, Wm, bias, nullptr, out);
    }
}